// Round 1
// baseline (3213.274 us; speedup 1.0000x reference)
//
#include <hip/hip_runtime.h>
#include <cstdint>
#include <cstddef>

#define SEQ   2049
#define NPAD  2176
#define BATCH 2
#define MPAD  (BATCH*NPAD)   // 4352
#define NH    8
#define DH    128

typedef __attribute__((ext_vector_type(8))) short s8v;
typedef __attribute__((ext_vector_type(4))) short s4v;
typedef __attribute__((ext_vector_type(4))) float f4v;

__device__ __forceinline__ short bf16_of(float f) {
  union { float f; unsigned u; } x; x.f = f;
  unsigned r = (x.u + 0x7fffu + ((x.u >> 16) & 1u)) >> 16;
  return (short)r;
}

__device__ __forceinline__ void async_cp16(const void* g, void* l) {
  __builtin_amdgcn_global_load_lds(
      (const __attribute__((address_space(1))) unsigned*)g,
      (__attribute__((address_space(3))) unsigned*)l, 16, 0, 0);
}

__device__ __forceinline__ f4v mfma16(s8v a, s8v b, f4v c) {
  return __builtin_amdgcn_mfma_f32_16x16x32_bf16(a, b, c, 0, 0, 0);
}

// ---------------------------------------------------------------------------
// concat cls + x -> xf (fp32 master, padded rows zeroed) and xb (bf16 copy)
// ---------------------------------------------------------------------------
__global__ void concat_cast(const float* __restrict__ x, const float* __restrict__ cls,
                            float* __restrict__ xf, short* __restrict__ xb)
{
  size_t idx = (size_t)blockIdx.x * 256 + threadIdx.x;
  size_t e = idx * 4;                       // 4 floats per thread
  size_t rowg = e >> 10;
  int d = (int)(e & 1023);
  int b = (int)(rowg / NPAD);
  int i = (int)(rowg % NPAD);
  float4 v;
  if (i == 0)            v = *(const float4*)(cls + d);
  else if (i <= 2048)    v = *(const float4*)(x + ((size_t)b * 2048 + (i - 1)) * 1024 + d);
  else                   v = make_float4(0.f, 0.f, 0.f, 0.f);
  *(float4*)(xf + e) = v;
  const float* vp = (const float*)&v;
  s4v sb;
#pragma unroll
  for (int j = 0; j < 4; j++) sb[j] = bf16_of(vp[j]);
  *(s4v*)(xb + e) = sb;
}

// ---------------------------------------------------------------------------
// weight cast fp32 (K,N) -> bf16 (N,K)  (transpose via LDS tile)
// ---------------------------------------------------------------------------
__global__ void wcast_t(const float* __restrict__ W, short* __restrict__ Wt, int K, int N)
{
  __shared__ float tile[64][65];
  int n0 = blockIdx.x * 64, k0 = blockIdx.y * 64;
  int tid = threadIdx.x;
#pragma unroll
  for (int i = 0; i < 16; i++) {
    int idx = i * 256 + tid;
    int r = idx >> 6, cc = idx & 63;
    tile[r][cc] = W[(size_t)(k0 + r) * N + n0 + cc];
  }
  __syncthreads();
#pragma unroll
  for (int i = 0; i < 16; i++) {
    int idx = i * 256 + tid;
    int r = idx >> 6, cc = idx & 63;     // r = n offset, cc = k offset
    Wt[(size_t)(n0 + r) * K + k0 + cc] = bf16_of(tile[cc][r]);
  }
}

// ---------------------------------------------------------------------------
// V transpose: qkv (B,NPAD,3072) v-part -> vT (B,H,DH,NPAD)  bf16
// ---------------------------------------------------------------------------
__global__ void v_transpose(const short* __restrict__ qkv, short* __restrict__ vT)
{
  __shared__ short tile[64][72];
  int nt = blockIdx.x;            // 0..33
  int hd = blockIdx.y;            // h*2 + dt
  int b  = blockIdx.z;
  int h = hd >> 1, dt = hd & 1;
  int n0 = nt * 64, d0 = dt * 64;
  int tid = threadIdx.x;
#pragma unroll
  for (int i = 0; i < 16; i++) {
    int idx = i * 256 + tid;
    int r = idx >> 6, cc = idx & 63;  // r = n offset, cc = d offset
    tile[r][cc] = qkv[((size_t)b * NPAD + n0 + r) * 3072 + 2048 + h * 128 + d0 + cc];
  }
  __syncthreads();
#pragma unroll
  for (int i = 0; i < 16; i++) {
    int idx = i * 256 + tid;
    int r = idx >> 6, cc = idx & 63;  // r = d offset, cc = n offset
    vT[((size_t)(b * NH + h) * DH + d0 + r) * NPAD + n0 + cc] = tile[cc][r];
  }
}

// ---------------------------------------------------------------------------
// GEMM: C(M x N) = A(M x K, bf16) * Bt(N x K, bf16)^T  [+bias][+gelu][+resid]
// EPI 0: out bf16.  EPI 1: +bias, gelu, out bf16.  EPI 2: +bias, +outf (fp32
// residual in/out, in-place) and bf16 copy.
// 128x128 tile, BK=64, 4 waves, global_load_lds w/ xor chunk swizzle.
// ---------------------------------------------------------------------------
template<int EPI>
__launch_bounds__(256, 2)
__global__ void gemm_bt(const short* __restrict__ A, const short* __restrict__ Bt,
                        const float* __restrict__ bias,
                        float* __restrict__ outf, short* __restrict__ outb,
                        int N, int K)
{
  __shared__ short As[128 * 64];
  __shared__ short Bs[128 * 64];
  const int tid = threadIdx.x;
  const int w = tid >> 6, l = tid & 63;
  const int quad = l >> 4, c = l & 15;
  const int wm = w & 1, wn = w >> 1;
  const size_t m0 = (size_t)blockIdx.y * 128;
  const size_t n0 = (size_t)blockIdx.x * 128;

  const f4v z4 = {0.f, 0.f, 0.f, 0.f};
  f4v acc[4][4];
#pragma unroll
  for (int i = 0; i < 4; i++)
#pragma unroll
    for (int j = 0; j < 4; j++) acc[i][j] = z4;

  const int ksteps = K >> 6;
  for (int ks = 0; ks < ksteps; ks++) {
    const int k0 = ks << 6;
    __syncthreads();
#pragma unroll
    for (int i = 0; i < 4; i++) {
      int chunk = (i * 4 + w) * 64 + l;      // 0..1023 : 16B chunks of the tile
      int row = chunk >> 3, kcs = chunk & 7;
      int gkc = kcs ^ (row & 7);             // xor swizzle
      async_cp16(A  + (m0 + row) * (size_t)K + k0 + gkc * 8, As + (i * 4 + w) * 512);
      async_cp16(Bt + (n0 + row) * (size_t)K + k0 + gkc * 8, Bs + (i * 4 + w) * 512);
    }
    __syncthreads();
#pragma unroll
    for (int kk = 0; kk < 2; kk++) {
      s8v af[4], bfr[4];
      const int kc = kk * 4 + quad;
#pragma unroll
      for (int mi = 0; mi < 4; mi++) {
        int m = wm * 64 + mi * 16 + c;
        af[mi] = *(const s8v*)(As + m * 64 + ((kc ^ (m & 7)) << 3));
      }
#pragma unroll
      for (int nj = 0; nj < 4; nj++) {
        int n = wn * 64 + nj * 16 + c;
        bfr[nj] = *(const s8v*)(Bs + n * 64 + ((kc ^ (n & 7)) << 3));
      }
#pragma unroll
      for (int mi = 0; mi < 4; mi++)
#pragma unroll
        for (int nj = 0; nj < 4; nj++)
          acc[mi][nj] = mfma16(af[mi], bfr[nj], acc[mi][nj]);
    }
  }

#pragma unroll
  for (int mi = 0; mi < 4; mi++) {
#pragma unroll
    for (int nj = 0; nj < 4; nj++) {
#pragma unroll
      for (int r = 0; r < 4; r++) {
        size_t row = m0 + wm * 64 + mi * 16 + quad * 4 + r;
        size_t col = n0 + wn * 64 + nj * 16 + c;
        float v = acc[mi][nj][r];
        if (EPI >= 1) v += bias[col];
        if (EPI == 1) v = 0.5f * v * (1.f + erff(v * 0.70710678118f));
        size_t off = row * (size_t)N + col;
        if (EPI == 2) {
          float res = outf[off] + v;
          outf[off] = res;
          outb[off] = bf16_of(res);
        } else {
          outb[off] = bf16_of(v);
        }
      }
    }
  }
}

// ---------------------------------------------------------------------------
// Flash attention, causal, scale = 1/sqrt(DIM) = 1/32 (per reference!).
// Block: 128 q-rows x one (batch, head). 4 waves, each wave 32 q-rows.
// ---------------------------------------------------------------------------
__launch_bounds__(256, 2)
__global__ void flash_attn(const short* __restrict__ qkv, const short* __restrict__ vT,
                           short* __restrict__ ao)
{
  __shared__ short Ks[64 * 128];   // [kv][dh]   swizzled
  __shared__ short Vs[128 * 64];   // [dh][kv]   swizzled
  __shared__ short Ps[128 * 72];   // [q][kv]    pad 72 (144B rows, 16B aligned)
  const int tid = threadIdx.x;
  const int w = tid >> 6, l = tid & 63;
  const int quad = l >> 4, c = l & 15;
  const int qt = blockIdx.x, h = blockIdx.y, b = blockIdx.z;
  const int q0 = qt * 128;
  const size_t qb = (size_t)b * NPAD * 3072;

  // Q fragments pinned in registers (A-operand: m = lane&15, k = quad*8+j)
  s8v qf[2][4];
#pragma unroll
  for (int mi = 0; mi < 2; mi++)
#pragma unroll
    for (int kd = 0; kd < 4; kd++) {
      int row = q0 + w * 32 + mi * 16 + c;
      qf[mi][kd] = *(const s8v*)(qkv + qb + (size_t)row * 3072 + h * 128 + kd * 32 + quad * 8);
    }

  const f4v z4 = {0.f, 0.f, 0.f, 0.f};
  f4v acco[2][8];
#pragma unroll
  for (int mi = 0; mi < 2; mi++)
#pragma unroll
    for (int dj = 0; dj < 8; dj++) acco[mi][dj] = z4;
  float mst[2][4], lst[2][4];
#pragma unroll
  for (int mi = 0; mi < 2; mi++)
#pragma unroll
    for (int r = 0; r < 4; r++) { mst[mi][r] = -__builtin_inff(); lst[mi][r] = 0.f; }

  const int tmaxq = (q0 + 127) >> 6;
  const int tmax = tmaxq < 32 ? tmaxq : 32;      // (SEQ-1)>>6 == 32
  for (int t = 0; t <= tmax; t++) {
    const int kv0 = t << 6;
    __syncthreads();
#pragma unroll
    for (int i = 0; i < 4; i++) {
      int chunk = (i * 4 + w) * 64 + l;
      int rK = chunk >> 4, kcsK = chunk & 15;    // K tile: 64 rows x 16 chunks
      async_cp16(qkv + qb + (size_t)(kv0 + rK) * 3072 + 1024 + h * 128 + ((kcsK ^ (rK & 15)) * 8),
                 Ks + (i * 4 + w) * 512);
      int rV = chunk >> 3, kcsV = chunk & 7;     // Vt tile: 128 rows x 8 chunks
      async_cp16(vT + ((size_t)(b * NH + h) * DH + rV) * NPAD + kv0 + ((kcsV ^ (rV & 7)) * 8),
                 Vs + (i * 4 + w) * 512);
    }
    __syncthreads();

    // S = Q K^T for this wave's 32 q-rows x 64 kv
    f4v accs[2][4];
#pragma unroll
    for (int mi = 0; mi < 2; mi++)
#pragma unroll
      for (int nj = 0; nj < 4; nj++) accs[mi][nj] = z4;
#pragma unroll
    for (int kd = 0; kd < 4; kd++) {
      const int kc = kd * 4 + quad;
#pragma unroll
      for (int nj = 0; nj < 4; nj++) {
        int n = nj * 16 + c;
        s8v kf = *(const s8v*)(Ks + n * 128 + ((kc ^ (n & 15)) << 3));
        accs[0][nj] = mfma16(qf[0][kd], kf, accs[0][nj]);
        accs[1][nj] = mfma16(qf[1][kd], kf, accs[1][nj]);
      }
    }

    const float scale = 0.03125f;   // DIM^-0.5 = 1/32
#pragma unroll
    for (int mi = 0; mi < 2; mi++) {
#pragma unroll
      for (int r = 0; r < 4; r++) {
        int qg = q0 + w * 32 + mi * 16 + quad * 4 + r;
        float s[4];
        float mx = -__builtin_inff();
#pragma unroll
        for (int nj = 0; nj < 4; nj++) {
          int kg = kv0 + nj * 16 + c;
          float v = accs[mi][nj][r] * scale;
          v = (kg > qg || kg >= SEQ) ? -__builtin_inff() : v;
          s[nj] = v;
          mx = fmaxf(mx, v);
        }
        mx = fmaxf(mx, __shfl_xor(mx, 1));
        mx = fmaxf(mx, __shfl_xor(mx, 2));
        mx = fmaxf(mx, __shfl_xor(mx, 4));
        mx = fmaxf(mx, __shfl_xor(mx, 8));
        float mn = fmaxf(mst[mi][r], mx);
        float a  = __expf(mst[mi][r] - mn);
        float rs = 0.f;
#pragma unroll
        for (int nj = 0; nj < 4; nj++) {
          float p = __expf(s[nj] - mn);
          rs += p;
          Ps[(w * 32 + mi * 16 + quad * 4 + r) * 72 + nj * 16 + c] = bf16_of(p);
        }
        rs += __shfl_xor(rs, 1);
        rs += __shfl_xor(rs, 2);
        rs += __shfl_xor(rs, 4);
        rs += __shfl_xor(rs, 8);
        mst[mi][r] = mn;
        lst[mi][r] = lst[mi][r] * a + rs;
#pragma unroll
        for (int dj = 0; dj < 8; dj++) acco[mi][dj][r] *= a;
      }
    }

    // O += P V   (P rows are wave-private; same-wave LDS ops are in-order)
#pragma unroll
    for (int kk = 0; kk < 2; kk++) {
      s8v pf[2];
#pragma unroll
      for (int mi = 0; mi < 2; mi++)
        pf[mi] = *(const s8v*)(Ps + (w * 32 + mi * 16 + c) * 72 + kk * 32 + quad * 8);
      const int kc = kk * 4 + quad;
#pragma unroll
      for (int dj = 0; dj < 8; dj++) {
        int n = dj * 16 + c;
        s8v vf = *(const s8v*)(Vs + n * 64 + ((kc ^ (n & 7)) << 3));
        acco[0][dj] = mfma16(pf[0], vf, acco[0][dj]);
        acco[1][dj] = mfma16(pf[1], vf, acco[1][dj]);
      }
    }
  }

#pragma unroll
  for (int mi = 0; mi < 2; mi++)
#pragma unroll
    for (int r = 0; r < 4; r++) {
      size_t row = (size_t)b * NPAD + q0 + w * 32 + mi * 16 + quad * 4 + r;
      float inv = 1.f / lst[mi][r];
#pragma unroll
      for (int dj = 0; dj < 8; dj++)
        ao[row * 1024 + h * 128 + dj * 16 + c] = bf16_of(acco[mi][dj][r] * inv);
    }
}

// ---------------------------------------------------------------------------
__global__ void cls_copy(const float* __restrict__ xf, float* __restrict__ out_cls)
{
  int idx = blockIdx.x * 256 + threadIdx.x;   // 2048 total
  int b = idx >> 10, d = idx & 1023;
  out_cls[idx] = xf[(size_t)b * NPAD * 1024 + d];
}

__global__ void final_copy(const float* __restrict__ xf, float* __restrict__ out)
{
  size_t idx = (size_t)blockIdx.x * 256 + threadIdx.x;  // 1,049,088 total (exact)
  size_t e = idx * 4;
  size_t r = e >> 10;
  int d = (int)(e & 1023);
  int b = (int)(r / SEQ);
  int i = (int)(r % SEQ);
  *(float4*)(out + e) = *(const float4*)(xf + ((size_t)b * NPAD + i) * 1024 + d);
}

// ---------------------------------------------------------------------------
extern "C" void kernel_launch(void* const* d_in, const int* in_sizes, int n_in,
                              void* d_out, int out_size, void* d_ws, size_t ws_size,
                              hipStream_t stream)
{
  const float* x   = (const float*)d_in[0];
  const float* cls = (const float*)d_in[1];
  const float* Wqkv_s[2] = {(const float*)d_in[2], (const float*)d_in[9]};
  const float* Wo_s[2]   = {(const float*)d_in[3], (const float*)d_in[10]};
  const float* bo_s[2]   = {(const float*)d_in[4], (const float*)d_in[11]};
  const float* W1_s[2]   = {(const float*)d_in[5], (const float*)d_in[12]};
  const float* b1_s[2]   = {(const float*)d_in[6], (const float*)d_in[13]};
  const float* W2_s[2]   = {(const float*)d_in[7], (const float*)d_in[14]};
  const float* b2_s[2]   = {(const float*)d_in[8], (const float*)d_in[15]};
  float* out = (float*)d_out;

  char* ws = (char*)d_ws;
  size_t off = 0;
  auto alloc = [&](size_t bytes) -> void* {
    void* p = ws + off;
    off += (bytes + 255) & ~(size_t)255;
    return p;
  };
  float* xf   = (float*)alloc((size_t)MPAD * 1024 * 4);
  short* xb   = (short*)alloc((size_t)MPAD * 1024 * 2);
  short* qkvb = (short*)alloc((size_t)MPAD * 3072 * 2);
  short* vT   = (short*)alloc((size_t)MPAD * 1024 * 2);
  short* aob  = (short*)alloc((size_t)MPAD * 1024 * 2);
  short* hb   = (short*)alloc((size_t)MPAD * 4096 * 2);
  short* wtq  = (short*)alloc((size_t)3072 * 1024 * 2);
  short* wto  = (short*)alloc((size_t)1024 * 1024 * 2);
  short* wt1  = (short*)alloc((size_t)4096 * 1024 * 2);
  short* wt2  = (short*)alloc((size_t)1024 * 4096 * 2);

  concat_cast<<<4352, 256, 0, stream>>>(x, cls, xf, xb);

  for (int layer = 0; layer < 8; layer++) {
    int s = layer >> 2, li = layer & 3;
    const float* Wqkv = Wqkv_s[s] + (size_t)li * 1024 * 3072;
    const float* Wo   = Wo_s[s]   + (size_t)li * 1024 * 1024;
    const float* bo   = bo_s[s]   + (size_t)li * 1024;
    const float* W1   = W1_s[s]   + (size_t)li * 1024 * 4096;
    const float* b1   = b1_s[s]   + (size_t)li * 4096;
    const float* W2   = W2_s[s]   + (size_t)li * 4096 * 1024;
    const float* b2   = b2_s[s]   + (size_t)li * 1024;

    wcast_t<<<dim3(48, 16), 256, 0, stream>>>(Wqkv, wtq, 1024, 3072);
    wcast_t<<<dim3(16, 16), 256, 0, stream>>>(Wo,   wto, 1024, 1024);
    wcast_t<<<dim3(64, 16), 256, 0, stream>>>(W1,   wt1, 1024, 4096);
    wcast_t<<<dim3(16, 64), 256, 0, stream>>>(W2,   wt2, 4096, 1024);

    // qkv = x @ Wqkv            (M=4352, N=3072, K=1024)
    gemm_bt<0><<<dim3(24, 34), 256, 0, stream>>>(xb, wtq, nullptr, nullptr, qkvb, 3072, 1024);
    v_transpose<<<dim3(34, 16, 2), 256, 0, stream>>>(qkvb, vT);
    flash_attn<<<dim3(17, 8, 2), 256, 0, stream>>>(qkvb, vT, aob);
    // x += attn @ Wo + bo       (N=1024, K=1024)
    gemm_bt<2><<<dim3(8, 34), 256, 0, stream>>>(aob, wto, bo, xf, xb, 1024, 1024);
    // h = gelu(x @ W1 + b1)     (N=4096, K=1024)
    gemm_bt<1><<<dim3(32, 34), 256, 0, stream>>>(xb, wt1, b1, nullptr, hb, 4096, 1024);
    // x += h @ W2 + b2          (N=1024, K=4096)
    gemm_bt<2><<<dim3(8, 34), 256, 0, stream>>>(hb, wt2, b2, xf, xb, 1024, 4096);

    if (layer == 3)
      cls_copy<<<8, 256, 0, stream>>>(xf, out + (size_t)BATCH * SEQ * 1024);
  }

  final_copy<<<4098, 256, 0, stream>>>(xf, out);
  (void)in_sizes; (void)n_in; (void)out_size; (void)ws_size;
}

// Round 2
// 2750.014 us; speedup vs baseline: 1.1685x; 1.1685x over previous
//
#include <hip/hip_runtime.h>
#include <cstdint>
#include <cstddef>

#define SEQ   2049
#define NPAD  2176
#define BATCH 2
#define MPAD  (BATCH*NPAD)   // 4352
#define NH    8
#define DH    128

typedef __attribute__((ext_vector_type(8))) short s8v;
typedef __attribute__((ext_vector_type(4))) short s4v;
typedef __attribute__((ext_vector_type(4))) float f4v;

__device__ __forceinline__ short bf16_of(float f) {
  union { float f; unsigned u; } x; x.f = f;
  unsigned r = (x.u + 0x7fffu + ((x.u >> 16) & 1u)) >> 16;
  return (short)r;
}

__device__ __forceinline__ void async_cp16(const void* g, void* l) {
  __builtin_amdgcn_global_load_lds(
      (const __attribute__((address_space(1))) unsigned*)g,
      (__attribute__((address_space(3))) unsigned*)l, 16, 0, 0);
}

__device__ __forceinline__ f4v mfma16(s8v a, s8v b, f4v c) {
  return __builtin_amdgcn_mfma_f32_16x16x32_bf16(a, b, c, 0, 0, 0);
}

// ---------------------------------------------------------------------------
// concat cls + x -> xf (fp32 master, padded rows zeroed) and xb (bf16 copy)
// ---------------------------------------------------------------------------
__global__ void concat_cast(const float* __restrict__ x, const float* __restrict__ cls,
                            float* __restrict__ xf, short* __restrict__ xb)
{
  size_t idx = (size_t)blockIdx.x * 256 + threadIdx.x;
  size_t e = idx * 4;                       // 4 floats per thread
  size_t rowg = e >> 10;
  int d = (int)(e & 1023);
  int b = (int)(rowg / NPAD);
  int i = (int)(rowg % NPAD);
  float4 v;
  if (i == 0)            v = *(const float4*)(cls + d);
  else if (i <= 2048)    v = *(const float4*)(x + ((size_t)b * 2048 + (i - 1)) * 1024 + d);
  else                   v = make_float4(0.f, 0.f, 0.f, 0.f);
  *(float4*)(xf + e) = v;
  const float* vp = (const float*)&v;
  s4v sb;
#pragma unroll
  for (int j = 0; j < 4; j++) sb[j] = bf16_of(vp[j]);
  *(s4v*)(xb + e) = sb;
}

// ---------------------------------------------------------------------------
// weight cast fp32 (K,N) -> bf16 (N,K), vectorized (float4 in, short4 out)
// ---------------------------------------------------------------------------
__global__ void wcast_t(const float* __restrict__ W, short* __restrict__ Wt, int K, int N)
{
  __shared__ float tile[64][65];
  int n0 = blockIdx.x * 64, k0 = blockIdx.y * 64;
  int tid = threadIdx.x;
#pragma unroll
  for (int i = 0; i < 4; i++) {
    int idx = i * 256 + tid;          // 1024 float4 = 64 rows x 16 chunks
    int r = idx >> 4, c4 = idx & 15;  // r = k offset, c4 = n chunk
    *(float4*)&tile[r][c4 * 4] = *(const float4*)(W + (size_t)(k0 + r) * N + n0 + c4 * 4);
  }
  __syncthreads();
#pragma unroll
  for (int i = 0; i < 4; i++) {
    int idx = i * 256 + tid;          // 1024 short4 = 64 n-rows x 16 k-chunks
    int n = idx >> 4, k4 = idx & 15;
    s4v v;
#pragma unroll
    for (int j = 0; j < 4; j++) v[j] = bf16_of(tile[k4 * 4 + j][n]);
    *(s4v*)(Wt + (size_t)(n0 + n) * K + k0 + k4 * 4) = v;
  }
}

// ---------------------------------------------------------------------------
// V transpose: qkv (B,NPAD,3072) v-part -> vT (B,H,DH,NPAD)  bf16
// ---------------------------------------------------------------------------
__global__ void v_transpose(const short* __restrict__ qkv, short* __restrict__ vT)
{
  __shared__ short tile[64][72];
  int nt = blockIdx.x;            // 0..33
  int hd = blockIdx.y;            // h*2 + dt
  int b  = blockIdx.z;
  int h = hd >> 1, dt = hd & 1;
  int n0 = nt * 64, d0 = dt * 64;
  int tid = threadIdx.x;
#pragma unroll
  for (int i = 0; i < 16; i++) {
    int idx = i * 256 + tid;
    int r = idx >> 6, cc = idx & 63;  // r = n offset, cc = d offset
    tile[r][cc] = qkv[((size_t)b * NPAD + n0 + r) * 3072 + 2048 + h * 128 + d0 + cc];
  }
  __syncthreads();
#pragma unroll
  for (int i = 0; i < 16; i++) {
    int idx = i * 256 + tid;
    int r = idx >> 6, cc = idx & 63;  // r = d offset, cc = n offset
    vT[((size_t)(b * NH + h) * DH + d0 + r) * NPAD + n0 + cc] = tile[cc][r];
  }
}

// ---------------------------------------------------------------------------
// GEMM 128x128: C(M x N) = A(M x K, bf16) * Bt(N x K, bf16)^T
// EPI 0: out bf16.  EPI 1: +bias, gelu, bf16.  EPI 2: +bias, fp32 resid
// in/out in-place + bf16 copy.
// ---------------------------------------------------------------------------
template<int EPI>
__launch_bounds__(256, 2)
__global__ void gemm_bt(const short* __restrict__ A, const short* __restrict__ Bt,
                        const float* __restrict__ bias,
                        float* __restrict__ outf, short* __restrict__ outb,
                        int N, int K)
{
  __shared__ short As[128 * 64];
  __shared__ short Bs[128 * 64];
  const int tid = threadIdx.x;
  const int w = tid >> 6, l = tid & 63;
  const int quad = l >> 4, c = l & 15;
  const int wm = w & 1, wn = w >> 1;
  const size_t m0 = (size_t)blockIdx.y * 128;
  const size_t n0 = (size_t)blockIdx.x * 128;

  const f4v z4 = {0.f, 0.f, 0.f, 0.f};
  f4v acc[4][4];
#pragma unroll
  for (int i = 0; i < 4; i++)
#pragma unroll
    for (int j = 0; j < 4; j++) acc[i][j] = z4;

  const int ksteps = K >> 6;
  for (int ks = 0; ks < ksteps; ks++) {
    const int k0 = ks << 6;
    __syncthreads();
#pragma unroll
    for (int i = 0; i < 4; i++) {
      int chunk = (i * 4 + w) * 64 + l;      // 0..1023 : 16B chunks of the tile
      int row = chunk >> 3, kcs = chunk & 7;
      int gkc = kcs ^ (row & 7);             // xor swizzle
      async_cp16(A  + (m0 + row) * (size_t)K + k0 + gkc * 8, As + (i * 4 + w) * 512);
      async_cp16(Bt + (n0 + row) * (size_t)K + k0 + gkc * 8, Bs + (i * 4 + w) * 512);
    }
    __syncthreads();
#pragma unroll
    for (int kk = 0; kk < 2; kk++) {
      s8v af[4], bfr[4];
      const int kc = kk * 4 + quad;
#pragma unroll
      for (int mi = 0; mi < 4; mi++) {
        int m = wm * 64 + mi * 16 + c;
        af[mi] = *(const s8v*)(As + m * 64 + ((kc ^ (m & 7)) << 3));
      }
#pragma unroll
      for (int nj = 0; nj < 4; nj++) {
        int n = wn * 64 + nj * 16 + c;
        bfr[nj] = *(const s8v*)(Bs + n * 64 + ((kc ^ (n & 7)) << 3));
      }
#pragma unroll
      for (int mi = 0; mi < 4; mi++)
#pragma unroll
        for (int nj = 0; nj < 4; nj++)
          acc[mi][nj] = mfma16(af[mi], bfr[nj], acc[mi][nj]);
    }
  }

#pragma unroll
  for (int mi = 0; mi < 4; mi++) {
#pragma unroll
    for (int nj = 0; nj < 4; nj++) {
#pragma unroll
      for (int r = 0; r < 4; r++) {
        size_t row = m0 + wm * 64 + mi * 16 + quad * 4 + r;
        size_t col = n0 + wn * 64 + nj * 16 + c;
        float v = acc[mi][nj][r];
        if (EPI >= 1) v += bias[col];
        if (EPI == 1) v = 0.5f * v * (1.f + erff(v * 0.70710678118f));
        size_t off = row * (size_t)N + col;
        if (EPI == 2) {
          float res = outf[off] + v;
          outf[off] = res;
          outb[off] = bf16_of(res);
        } else {
          outb[off] = bf16_of(v);
        }
      }
    }
  }
}

// ---------------------------------------------------------------------------
// GEMM 64x128 tile (for small-N GEMMs: more blocks, higher occupancy)
// ---------------------------------------------------------------------------
template<int EPI>
__launch_bounds__(256, 4)
__global__ void gemm_bt64(const short* __restrict__ A, const short* __restrict__ Bt,
                          const float* __restrict__ bias,
                          float* __restrict__ outf, short* __restrict__ outb,
                          int N, int K)
{
  __shared__ short As[64 * 64];
  __shared__ short Bs[128 * 64];
  const int tid = threadIdx.x;
  const int w = tid >> 6, l = tid & 63;
  const int quad = l >> 4, c = l & 15;
  const int wm = w & 1, wn = w >> 1;
  const size_t m0 = (size_t)blockIdx.y * 64;
  const size_t n0 = (size_t)blockIdx.x * 128;

  const f4v z4 = {0.f, 0.f, 0.f, 0.f};
  f4v acc[2][4];
#pragma unroll
  for (int i = 0; i < 2; i++)
#pragma unroll
    for (int j = 0; j < 4; j++) acc[i][j] = z4;

  const int ksteps = K >> 6;
  for (int ks = 0; ks < ksteps; ks++) {
    const int k0 = ks << 6;
    __syncthreads();
#pragma unroll
    for (int i = 0; i < 2; i++) {          // A: 512 chunks
      int chunk = (i * 4 + w) * 64 + l;
      int row = chunk >> 3, kcs = chunk & 7;
      int gkc = kcs ^ (row & 7);
      async_cp16(A + (m0 + row) * (size_t)K + k0 + gkc * 8, As + (i * 4 + w) * 512);
    }
#pragma unroll
    for (int i = 0; i < 4; i++) {          // B: 1024 chunks
      int chunk = (i * 4 + w) * 64 + l;
      int row = chunk >> 3, kcs = chunk & 7;
      int gkc = kcs ^ (row & 7);
      async_cp16(Bt + (n0 + row) * (size_t)K + k0 + gkc * 8, Bs + (i * 4 + w) * 512);
    }
    __syncthreads();
#pragma unroll
    for (int kk = 0; kk < 2; kk++) {
      s8v af[2], bfr[4];
      const int kc = kk * 4 + quad;
#pragma unroll
      for (int mi = 0; mi < 2; mi++) {
        int m = wm * 32 + mi * 16 + c;
        af[mi] = *(const s8v*)(As + m * 64 + ((kc ^ (m & 7)) << 3));
      }
#pragma unroll
      for (int nj = 0; nj < 4; nj++) {
        int n = wn * 64 + nj * 16 + c;
        bfr[nj] = *(const s8v*)(Bs + n * 64 + ((kc ^ (n & 7)) << 3));
      }
#pragma unroll
      for (int mi = 0; mi < 2; mi++)
#pragma unroll
        for (int nj = 0; nj < 4; nj++)
          acc[mi][nj] = mfma16(af[mi], bfr[nj], acc[mi][nj]);
    }
  }

#pragma unroll
  for (int mi = 0; mi < 2; mi++) {
#pragma unroll
    for (int nj = 0; nj < 4; nj++) {
#pragma unroll
      for (int r = 0; r < 4; r++) {
        size_t row = m0 + wm * 32 + mi * 16 + quad * 4 + r;
        size_t col = n0 + wn * 64 + nj * 16 + c;
        float v = acc[mi][nj][r];
        if (EPI >= 1) v += bias[col];
        if (EPI == 1) v = 0.5f * v * (1.f + erff(v * 0.70710678118f));
        size_t off = row * (size_t)N + col;
        if (EPI == 2) {
          float res = outf[off] + v;
          outf[off] = res;
          outb[off] = bf16_of(res);
        } else {
          outb[off] = bf16_of(v);
        }
      }
    }
  }
}

// ---------------------------------------------------------------------------
// Flash attention, causal, scale = 1/sqrt(DIM) = 1/32 (per reference!).
// 64 q-rows per block (one 16-row MFMA strip per wave). Reversed qt order
// so the long (high-q0) blocks launch first.
// ---------------------------------------------------------------------------
__launch_bounds__(256, 3)
__global__ void flash_attn(const short* __restrict__ qkv, const short* __restrict__ vT,
                           short* __restrict__ ao)
{
  __shared__ short Ks[64 * 128];   // [kv][dh]   swizzled
  __shared__ short Vs[128 * 64];   // [dh][kv]   swizzled
  __shared__ short Ps[64 * 72];    // [q][kv]    pad 72 (144B rows, 16B aligned)
  const int tid = threadIdx.x;
  const int w = tid >> 6, l = tid & 63;
  const int quad = l >> 4, c = l & 15;
  const int qt = 32 - blockIdx.x;  // reversed: longest blocks first
  const int h = blockIdx.y, b = blockIdx.z;
  const int q0 = qt * 64;
  const size_t qb = (size_t)b * NPAD * 3072;

  // Q fragments pinned in registers (A-operand: m = lane&15, k = quad*8+j)
  s8v qf[4];
#pragma unroll
  for (int kd = 0; kd < 4; kd++) {
    int row = q0 + w * 16 + c;
    qf[kd] = *(const s8v*)(qkv + qb + (size_t)row * 3072 + h * 128 + kd * 32 + quad * 8);
  }

  const f4v z4 = {0.f, 0.f, 0.f, 0.f};
  f4v acco[8];
#pragma unroll
  for (int dj = 0; dj < 8; dj++) acco[dj] = z4;
  float mst[4], lst[4];
#pragma unroll
  for (int r = 0; r < 4; r++) { mst[r] = -__builtin_inff(); lst[r] = 0.f; }

  const int tmaxq = (q0 + 63) >> 6;
  const int tmax = tmaxq < 32 ? tmaxq : 32;      // (SEQ-1)>>6 == 32
  for (int t = 0; t <= tmax; t++) {
    const int kv0 = t << 6;
    __syncthreads();
#pragma unroll
    for (int i = 0; i < 4; i++) {
      int chunk = (i * 4 + w) * 64 + l;
      int rK = chunk >> 4, kcsK = chunk & 15;    // K tile: 64 rows x 16 chunks
      async_cp16(qkv + qb + (size_t)(kv0 + rK) * 3072 + 1024 + h * 128 + ((kcsK ^ (rK & 15)) * 8),
                 Ks + (i * 4 + w) * 512);
      int rV = chunk >> 3, kcsV = chunk & 7;     // Vt tile: 128 rows x 8 chunks
      async_cp16(vT + ((size_t)(b * NH + h) * DH + rV) * NPAD + kv0 + ((kcsV ^ (rV & 7)) * 8),
                 Vs + (i * 4 + w) * 512);
    }
    __syncthreads();

    // S = Q K^T for this wave's 16 q-rows x 64 kv
    f4v accs[4];
#pragma unroll
    for (int nj = 0; nj < 4; nj++) accs[nj] = z4;
#pragma unroll
    for (int kd = 0; kd < 4; kd++) {
      const int kc = kd * 4 + quad;
#pragma unroll
      for (int nj = 0; nj < 4; nj++) {
        int n = nj * 16 + c;
        s8v kf = *(const s8v*)(Ks + n * 128 + ((kc ^ (n & 15)) << 3));
        accs[nj] = mfma16(qf[kd], kf, accs[nj]);
      }
    }

    const float scale = 0.03125f;   // DIM^-0.5 = 1/32
#pragma unroll
    for (int r = 0; r < 4; r++) {
      int qg = q0 + w * 16 + quad * 4 + r;
      float s[4];
      float mx = -__builtin_inff();
#pragma unroll
      for (int nj = 0; nj < 4; nj++) {
        int kg = kv0 + nj * 16 + c;
        float v = accs[nj][r] * scale;
        v = (kg > qg || kg >= SEQ) ? -__builtin_inff() : v;
        s[nj] = v;
        mx = fmaxf(mx, v);
      }
      mx = fmaxf(mx, __shfl_xor(mx, 1));
      mx = fmaxf(mx, __shfl_xor(mx, 2));
      mx = fmaxf(mx, __shfl_xor(mx, 4));
      mx = fmaxf(mx, __shfl_xor(mx, 8));
      float mn = fmaxf(mst[r], mx);
      float a  = __expf(mst[r] - mn);
      float rs = 0.f;
#pragma unroll
      for (int nj = 0; nj < 4; nj++) {
        float p = __expf(s[nj] - mn);
        rs += p;
        Ps[(w * 16 + quad * 4 + r) * 72 + nj * 16 + c] = bf16_of(p);
      }
      rs += __shfl_xor(rs, 1);
      rs += __shfl_xor(rs, 2);
      rs += __shfl_xor(rs, 4);
      rs += __shfl_xor(rs, 8);
      mst[r] = mn;
      lst[r] = lst[r] * a + rs;
#pragma unroll
      for (int dj = 0; dj < 8; dj++) acco[dj][r] *= a;
    }

    // O += P V   (P rows are wave-private; same-wave LDS ops are in-order)
#pragma unroll
    for (int kk = 0; kk < 2; kk++) {
      s8v pf = *(const s8v*)(Ps + (w * 16 + c) * 72 + kk * 32 + quad * 8);
      const int kc = kk * 4 + quad;
#pragma unroll
      for (int dj = 0; dj < 8; dj++) {
        int n = dj * 16 + c;
        s8v vf = *(const s8v*)(Vs + n * 64 + ((kc ^ (n & 7)) << 3));
        acco[dj] = mfma16(pf, vf, acco[dj]);
      }
    }
  }

#pragma unroll
  for (int r = 0; r < 4; r++) {
    size_t row = (size_t)b * NPAD + q0 + w * 16 + quad * 4 + r;
    float inv = 1.f / lst[r];
#pragma unroll
    for (int dj = 0; dj < 8; dj++)
      ao[row * 1024 + h * 128 + dj * 16 + c] = bf16_of(acco[dj][r] * inv);
  }
}

// ---------------------------------------------------------------------------
__global__ void cls_copy(const float* __restrict__ xf, float* __restrict__ out_cls)
{
  int idx = blockIdx.x * 256 + threadIdx.x;   // 2048 total
  int b = idx >> 10, d = idx & 1023;
  out_cls[idx] = xf[(size_t)b * NPAD * 1024 + d];
}

__global__ void final_copy(const float* __restrict__ xf, float* __restrict__ out)
{
  size_t idx = (size_t)blockIdx.x * 256 + threadIdx.x;  // 1,049,088 total (exact)
  size_t e = idx * 4;
  size_t r = e >> 10;
  int d = (int)(e & 1023);
  int b = (int)(r / SEQ);
  int i = (int)(r % SEQ);
  *(float4*)(out + e) = *(const float4*)(xf + ((size_t)b * NPAD + i) * 1024 + d);
}

// ---------------------------------------------------------------------------
extern "C" void kernel_launch(void* const* d_in, const int* in_sizes, int n_in,
                              void* d_out, int out_size, void* d_ws, size_t ws_size,
                              hipStream_t stream)
{
  const float* x   = (const float*)d_in[0];
  const float* cls = (const float*)d_in[1];
  const float* Wqkv_s[2] = {(const float*)d_in[2], (const float*)d_in[9]};
  const float* Wo_s[2]   = {(const float*)d_in[3], (const float*)d_in[10]};
  const float* bo_s[2]   = {(const float*)d_in[4], (const float*)d_in[11]};
  const float* W1_s[2]   = {(const float*)d_in[5], (const float*)d_in[12]};
  const float* b1_s[2]   = {(const float*)d_in[6], (const float*)d_in[13]};
  const float* W2_s[2]   = {(const float*)d_in[7], (const float*)d_in[14]};
  const float* b2_s[2]   = {(const float*)d_in[8], (const float*)d_in[15]};
  float* out = (float*)d_out;

  char* ws = (char*)d_ws;
  size_t off = 0;
  auto alloc = [&](size_t bytes) -> void* {
    void* p = ws + off;
    off += (bytes + 255) & ~(size_t)255;
    return p;
  };
  float* xf   = (float*)alloc((size_t)MPAD * 1024 * 4);
  short* xb   = (short*)alloc((size_t)MPAD * 1024 * 2);
  short* qkvb = (short*)alloc((size_t)MPAD * 3072 * 2);
  short* vT   = (short*)alloc((size_t)MPAD * 1024 * 2);
  short* aob  = (short*)alloc((size_t)MPAD * 1024 * 2);
  short* hb   = (short*)alloc((size_t)MPAD * 4096 * 2);
  short* wtq  = (short*)alloc((size_t)3072 * 1024 * 2);
  short* wto  = (short*)alloc((size_t)1024 * 1024 * 2);
  short* wt1  = (short*)alloc((size_t)4096 * 1024 * 2);
  short* wt2  = (short*)alloc((size_t)1024 * 4096 * 2);

  concat_cast<<<4352, 256, 0, stream>>>(x, cls, xf, xb);

  for (int layer = 0; layer < 8; layer++) {
    int s = layer >> 2, li = layer & 3;
    const float* Wqkv = Wqkv_s[s] + (size_t)li * 1024 * 3072;
    const float* Wo   = Wo_s[s]   + (size_t)li * 1024 * 1024;
    const float* bo   = bo_s[s]   + (size_t)li * 1024;
    const float* W1   = W1_s[s]   + (size_t)li * 1024 * 4096;
    const float* b1   = b1_s[s]   + (size_t)li * 4096;
    const float* W2   = W2_s[s]   + (size_t)li * 4096 * 1024;
    const float* b2   = b2_s[s]   + (size_t)li * 1024;

    wcast_t<<<dim3(48, 16), 256, 0, stream>>>(Wqkv, wtq, 1024, 3072);
    wcast_t<<<dim3(16, 16), 256, 0, stream>>>(Wo,   wto, 1024, 1024);
    wcast_t<<<dim3(64, 16), 256, 0, stream>>>(W1,   wt1, 1024, 4096);
    wcast_t<<<dim3(16, 64), 256, 0, stream>>>(W2,   wt2, 4096, 1024);

    // qkv = x @ Wqkv            (M=4352, N=3072, K=1024)
    gemm_bt<0><<<dim3(24, 34), 256, 0, stream>>>(xb, wtq, nullptr, nullptr, qkvb, 3072, 1024);
    v_transpose<<<dim3(34, 16, 2), 256, 0, stream>>>(qkvb, vT);
    flash_attn<<<dim3(33, 8, 2), 256, 0, stream>>>(qkvb, vT, aob);
    // x += attn @ Wo + bo       (N=1024, K=1024)
    gemm_bt64<2><<<dim3(8, 68), 256, 0, stream>>>(aob, wto, bo, xf, xb, 1024, 1024);
    // h = gelu(x @ W1 + b1)     (N=4096, K=1024)
    gemm_bt<1><<<dim3(32, 34), 256, 0, stream>>>(xb, wt1, b1, nullptr, hb, 4096, 1024);
    // x += h @ W2 + b2          (N=1024, K=4096)
    gemm_bt64<2><<<dim3(8, 68), 256, 0, stream>>>(hb, wt2, b2, xf, xb, 1024, 4096);

    if (layer == 3)
      cls_copy<<<8, 256, 0, stream>>>(xf, out + (size_t)BATCH * SEQ * 1024);
  }

  final_copy<<<4098, 256, 0, stream>>>(xf, out);
  (void)in_sizes; (void)n_in; (void)out_size; (void)ws_size;
}

// Round 3
// 2515.211 us; speedup vs baseline: 1.2775x; 1.0934x over previous
//
#include <hip/hip_runtime.h>
#include <cstdint>
#include <cstddef>

#define SEQ   2049
#define NPAD  2176
#define BATCH 2
#define MPAD  (BATCH*NPAD)   // 4352
#define NH    8
#define DH    128

typedef __attribute__((ext_vector_type(8))) short s8v;
typedef __attribute__((ext_vector_type(4))) short s4v;
typedef __attribute__((ext_vector_type(4))) float f4v;

__device__ __forceinline__ short bf16_of(float f) {
  union { float f; unsigned u; } x; x.f = f;
  unsigned r = (x.u + 0x7fffu + ((x.u >> 16) & 1u)) >> 16;
  return (short)r;
}

__device__ __forceinline__ void async_cp16(const void* g, void* l) {
  __builtin_amdgcn_global_load_lds(
      (const __attribute__((address_space(1))) unsigned*)g,
      (__attribute__((address_space(3))) unsigned*)l, 16, 0, 0);
}

__device__ __forceinline__ f4v mfma16(s8v a, s8v b, f4v c) {
  return __builtin_amdgcn_mfma_f32_16x16x32_bf16(a, b, c, 0, 0, 0);
}

// ---------------------------------------------------------------------------
// concat cls + x -> xf (fp32 master, padded rows zeroed) and xb (bf16 copy)
// ---------------------------------------------------------------------------
__global__ void concat_cast(const float* __restrict__ x, const float* __restrict__ cls,
                            float* __restrict__ xf, short* __restrict__ xb)
{
  size_t idx = (size_t)blockIdx.x * 256 + threadIdx.x;
  size_t e = idx * 4;                       // 4 floats per thread
  size_t rowg = e >> 10;
  int d = (int)(e & 1023);
  int b = (int)(rowg / NPAD);
  int i = (int)(rowg % NPAD);
  float4 v;
  if (i == 0)            v = *(const float4*)(cls + d);
  else if (i <= 2048)    v = *(const float4*)(x + ((size_t)b * 2048 + (i - 1)) * 1024 + d);
  else                   v = make_float4(0.f, 0.f, 0.f, 0.f);
  *(float4*)(xf + e) = v;
  const float* vp = (const float*)&v;
  s4v sb;
#pragma unroll
  for (int j = 0; j < 4; j++) sb[j] = bf16_of(vp[j]);
  *(s4v*)(xb + e) = sb;
}

// ---------------------------------------------------------------------------
// All 4 weight casts of one layer in ONE launch.  fp32 (K,N) -> bf16 (N,K).
// Tile decode: Wqkv 48x16=768, Wo 16x16=256, W1 64x16=1024, W2 16x64=1024.
// ---------------------------------------------------------------------------
__global__ void wcast_all(const float* __restrict__ Wq, const float* __restrict__ Wo,
                          const float* __restrict__ W1f, const float* __restrict__ W2f,
                          short* __restrict__ wtq, short* __restrict__ wto,
                          short* __restrict__ wt1, short* __restrict__ wt2)
{
  int bx = blockIdx.x;
  const float* W; short* Wt; int K, N;
  if (bx < 768)       { W = Wq;  Wt = wtq; K = 1024; N = 3072; }
  else if (bx < 1024) { bx -= 768;  W = Wo;  Wt = wto; K = 1024; N = 1024; }
  else if (bx < 2048) { bx -= 1024; W = W1f; Wt = wt1; K = 1024; N = 4096; }
  else                { bx -= 2048; W = W2f; Wt = wt2; K = 4096; N = 1024; }
  int nt = N >> 6;
  int n0 = (bx % nt) * 64, k0 = (bx / nt) * 64;

  __shared__ float tile[64][65];
  int tid = threadIdx.x;
#pragma unroll
  for (int i = 0; i < 4; i++) {
    int idx = i * 256 + tid;          // 1024 float4 = 64 rows x 16 chunks
    int r = idx >> 4, c4 = idx & 15;  // r = k offset, c4 = n chunk
    *(float4*)&tile[r][c4 * 4] = *(const float4*)(W + (size_t)(k0 + r) * N + n0 + c4 * 4);
  }
  __syncthreads();
#pragma unroll
  for (int i = 0; i < 4; i++) {
    int idx = i * 256 + tid;          // 1024 short4 = 64 n-rows x 16 k-chunks
    int n = idx >> 4, k4 = idx & 15;
    s4v v;
#pragma unroll
    for (int j = 0; j < 4; j++) v[j] = bf16_of(tile[k4 * 4 + j][n]);
    *(s4v*)(Wt + (size_t)(n0 + n) * K + k0 + k4 * 4) = v;
  }
}

// ---------------------------------------------------------------------------
// V transpose: qkv (B,NPAD,3072) v-part -> vT (B,H,DH,NPAD)  bf16
// ---------------------------------------------------------------------------
__global__ void v_transpose(const short* __restrict__ qkv, short* __restrict__ vT)
{
  __shared__ short tile[64][72];
  int nt = blockIdx.x;            // 0..33
  int hd = blockIdx.y;            // h*2 + dt
  int b  = blockIdx.z;
  int h = hd >> 1, dt = hd & 1;
  int n0 = nt * 64, d0 = dt * 64;
  int tid = threadIdx.x;
#pragma unroll
  for (int i = 0; i < 16; i++) {
    int idx = i * 256 + tid;
    int r = idx >> 6, cc = idx & 63;  // r = n offset, cc = d offset
    tile[r][cc] = qkv[((size_t)b * NPAD + n0 + r) * 3072 + 2048 + h * 128 + d0 + cc];
  }
  __syncthreads();
#pragma unroll
  for (int i = 0; i < 16; i++) {
    int idx = i * 256 + tid;
    int r = idx >> 6, cc = idx & 63;  // r = d offset, cc = n offset
    vT[((size_t)(b * NH + h) * DH + d0 + r) * NPAD + n0 + cc] = tile[cc][r];
  }
}

// ---------------------------------------------------------------------------
// GEMM 128x128: C(M x N) = A(M x K, bf16) * Bt(N x K, bf16)^T
// EPI 0: out bf16.  EPI 1: +bias, gelu, bf16.  EPI 2: +bias, fp32 resid
// in/out in-place + bf16 copy.
// ---------------------------------------------------------------------------
template<int EPI>
__launch_bounds__(256, 2)
__global__ void gemm_bt(const short* __restrict__ A, const short* __restrict__ Bt,
                        const float* __restrict__ bias,
                        float* __restrict__ outf, short* __restrict__ outb,
                        int N, int K)
{
  __shared__ short As[128 * 64];
  __shared__ short Bs[128 * 64];
  const int tid = threadIdx.x;
  const int w = tid >> 6, l = tid & 63;
  const int quad = l >> 4, c = l & 15;
  const int wm = w & 1, wn = w >> 1;
  const size_t m0 = (size_t)blockIdx.y * 128;
  const size_t n0 = (size_t)blockIdx.x * 128;

  const f4v z4 = {0.f, 0.f, 0.f, 0.f};
  f4v acc[4][4];
#pragma unroll
  for (int i = 0; i < 4; i++)
#pragma unroll
    for (int j = 0; j < 4; j++) acc[i][j] = z4;

  const int ksteps = K >> 6;
  for (int ks = 0; ks < ksteps; ks++) {
    const int k0 = ks << 6;
    __syncthreads();
#pragma unroll
    for (int i = 0; i < 4; i++) {
      int chunk = (i * 4 + w) * 64 + l;      // 0..1023 : 16B chunks of the tile
      int row = chunk >> 3, kcs = chunk & 7;
      int gkc = kcs ^ (row & 7);             // xor swizzle
      async_cp16(A  + (m0 + row) * (size_t)K + k0 + gkc * 8, As + (i * 4 + w) * 512);
      async_cp16(Bt + (n0 + row) * (size_t)K + k0 + gkc * 8, Bs + (i * 4 + w) * 512);
    }
    __syncthreads();
#pragma unroll
    for (int kk = 0; kk < 2; kk++) {
      s8v af[4], bfr[4];
      const int kc = kk * 4 + quad;
#pragma unroll
      for (int mi = 0; mi < 4; mi++) {
        int m = wm * 64 + mi * 16 + c;
        af[mi] = *(const s8v*)(As + m * 64 + ((kc ^ (m & 7)) << 3));
      }
#pragma unroll
      for (int nj = 0; nj < 4; nj++) {
        int n = wn * 64 + nj * 16 + c;
        bfr[nj] = *(const s8v*)(Bs + n * 64 + ((kc ^ (n & 7)) << 3));
      }
#pragma unroll
      for (int mi = 0; mi < 4; mi++)
#pragma unroll
        for (int nj = 0; nj < 4; nj++)
          acc[mi][nj] = mfma16(af[mi], bfr[nj], acc[mi][nj]);
    }
  }

#pragma unroll
  for (int mi = 0; mi < 4; mi++) {
#pragma unroll
    for (int nj = 0; nj < 4; nj++) {
#pragma unroll
      for (int r = 0; r < 4; r++) {
        size_t row = m0 + wm * 64 + mi * 16 + quad * 4 + r;
        size_t col = n0 + wn * 64 + nj * 16 + c;
        float v = acc[mi][nj][r];
        if (EPI >= 1) v += bias[col];
        if (EPI == 1) v = 0.5f * v * (1.f + erff(v * 0.70710678118f));
        size_t off = row * (size_t)N + col;
        if (EPI == 2) {
          float res = outf[off] + v;
          outf[off] = res;
          outb[off] = bf16_of(res);
        } else {
          outb[off] = bf16_of(v);
        }
      }
    }
  }
}

// ---------------------------------------------------------------------------
// GEMM 64x128 tile (for small-N GEMMs: more blocks, higher occupancy)
// ---------------------------------------------------------------------------
template<int EPI>
__launch_bounds__(256, 4)
__global__ void gemm_bt64(const short* __restrict__ A, const short* __restrict__ Bt,
                          const float* __restrict__ bias,
                          float* __restrict__ outf, short* __restrict__ outb,
                          int N, int K)
{
  __shared__ short As[64 * 64];
  __shared__ short Bs[128 * 64];
  const int tid = threadIdx.x;
  const int w = tid >> 6, l = tid & 63;
  const int quad = l >> 4, c = l & 15;
  const int wm = w & 1, wn = w >> 1;
  const size_t m0 = (size_t)blockIdx.y * 64;
  const size_t n0 = (size_t)blockIdx.x * 128;

  const f4v z4 = {0.f, 0.f, 0.f, 0.f};
  f4v acc[2][4];
#pragma unroll
  for (int i = 0; i < 2; i++)
#pragma unroll
    for (int j = 0; j < 4; j++) acc[i][j] = z4;

  const int ksteps = K >> 6;
  for (int ks = 0; ks < ksteps; ks++) {
    const int k0 = ks << 6;
    __syncthreads();
#pragma unroll
    for (int i = 0; i < 2; i++) {          // A: 512 chunks
      int chunk = (i * 4 + w) * 64 + l;
      int row = chunk >> 3, kcs = chunk & 7;
      int gkc = kcs ^ (row & 7);
      async_cp16(A + (m0 + row) * (size_t)K + k0 + gkc * 8, As + (i * 4 + w) * 512);
    }
#pragma unroll
    for (int i = 0; i < 4; i++) {          // B: 1024 chunks
      int chunk = (i * 4 + w) * 64 + l;
      int row = chunk >> 3, kcs = chunk & 7;
      int gkc = kcs ^ (row & 7);
      async_cp16(Bt + (n0 + row) * (size_t)K + k0 + gkc * 8, Bs + (i * 4 + w) * 512);
    }
    __syncthreads();
#pragma unroll
    for (int kk = 0; kk < 2; kk++) {
      s8v af[2], bfr[4];
      const int kc = kk * 4 + quad;
#pragma unroll
      for (int mi = 0; mi < 2; mi++) {
        int m = wm * 32 + mi * 16 + c;
        af[mi] = *(const s8v*)(As + m * 64 + ((kc ^ (m & 7)) << 3));
      }
#pragma unroll
      for (int nj = 0; nj < 4; nj++) {
        int n = wn * 64 + nj * 16 + c;
        bfr[nj] = *(const s8v*)(Bs + n * 64 + ((kc ^ (n & 7)) << 3));
      }
#pragma unroll
      for (int mi = 0; mi < 2; mi++)
#pragma unroll
        for (int nj = 0; nj < 4; nj++)
          acc[mi][nj] = mfma16(af[mi], bfr[nj], acc[mi][nj]);
    }
  }

#pragma unroll
  for (int mi = 0; mi < 2; mi++) {
#pragma unroll
    for (int nj = 0; nj < 4; nj++) {
#pragma unroll
      for (int r = 0; r < 4; r++) {
        size_t row = m0 + wm * 32 + mi * 16 + quad * 4 + r;
        size_t col = n0 + wn * 64 + nj * 16 + c;
        float v = acc[mi][nj][r];
        if (EPI >= 1) v += bias[col];
        if (EPI == 1) v = 0.5f * v * (1.f + erff(v * 0.70710678118f));
        size_t off = row * (size_t)N + col;
        if (EPI == 2) {
          float res = outf[off] + v;
          outf[off] = res;
          outb[off] = bf16_of(res);
        } else {
          outb[off] = bf16_of(v);
        }
      }
    }
  }
}

// ---------------------------------------------------------------------------
// Flash attention v3: S^T layout (2 shuffles instead of 32 per iter) +
// double-buffered K/V prefetch (static buffers, 1 barrier per tile).
// 64 q-rows/block, wave w owns q-rows w*16..w*16+15 (lane&15 = q).
// scale = 1/sqrt(DIM) = 1/32 per reference.
// ---------------------------------------------------------------------------
__launch_bounds__(256, 4)
__global__ void flash_attn(const short* __restrict__ qkv, const short* __restrict__ vT,
                           short* __restrict__ ao)
{
  __shared__ short Ks0[64 * 128];  // [kv][dh] swizzled (16 chunks, xor row&15)
  __shared__ short Ks1[64 * 128];
  __shared__ short Vs0[128 * 64];  // [dh][kv] swizzled (8 chunks, xor row&7)
  __shared__ short Vs1[128 * 64];
  __shared__ short Pt[64 * 72];    // [q][kv] pad 72 (144B rows)
  const int tid = threadIdx.x;
  const int w = tid >> 6, l = tid & 63;
  const int quad = l >> 4, c = l & 15;
  const int qt = 32 - blockIdx.x;  // reversed: longest blocks first
  const int h = blockIdx.y, b = blockIdx.z;
  const int q0 = qt * 64;
  const int qg = q0 + w * 16 + c;  // this lane's q row (global, within batch)
  const size_t qb = (size_t)b * NPAD * 3072;
  const size_t vb = (size_t)(b * NH + h) * DH;

  // Q fragment (B-operand: n = lane&15 = q, k = quad*8+j), rows w*16+c
  s8v qf[4];
#pragma unroll
  for (int kd = 0; kd < 4; kd++)
    qf[kd] = *(const s8v*)(qkv + qb + (size_t)(q0 + w * 16 + c) * 3072 + h * 128 + kd * 32 + quad * 8);

  const f4v z4 = {0.f, 0.f, 0.f, 0.f};
  f4v acco[8];                     // O^T: d = dj*16+quad*4+r, q = c
#pragma unroll
  for (int dj = 0; dj < 8; dj++) acco[dj] = z4;
  float m_run = -__builtin_inff(), l_run = 0.f;

  auto do_prefetch = [&](int t, short* Ksb, short* Vsb) {
    const int kv0 = t << 6;
#pragma unroll
    for (int i = 0; i < 4; i++) {
      int chunk = (i * 4 + w) * 64 + l;
      int rK = chunk >> 4, kcsK = chunk & 15;    // K tile: 64 rows x 16 chunks
      async_cp16(qkv + qb + (size_t)(kv0 + rK) * 3072 + 1024 + h * 128 + ((kcsK ^ (rK & 15)) * 8),
                 Ksb + (i * 4 + w) * 512);
      int rV = chunk >> 3, kcsV = chunk & 7;     // Vt tile: 128 rows x 8 chunks
      async_cp16(vT + (vb + rV) * NPAD + kv0 + ((kcsV ^ (rV & 7)) * 8),
                 Vsb + (i * 4 + w) * 512);
    }
  };

  auto do_tile = [&](int t, const short* Ksb, const short* Vsb) {
    const int kv0 = t << 6;
    // S^T = K * Q^T : accs[nj] C-layout: kg = kv0+nj*16+quad*4+r, q = c
    f4v accs[4];
#pragma unroll
    for (int nj = 0; nj < 4; nj++) accs[nj] = z4;
#pragma unroll
    for (int kd = 0; kd < 4; kd++) {
      const int kc = kd * 4 + quad;
#pragma unroll
      for (int nj = 0; nj < 4; nj++) {
        int m = nj * 16 + c;
        s8v kf = *(const s8v*)(Ksb + m * 128 + ((kc ^ (m & 15)) << 3));
        accs[nj] = mfma16(kf, qf[kd], accs[nj]);
      }
    }

    const float scale = 0.03125f;   // DIM^-0.5 = 1/32
    float sv[4][4];
    float tmx = -__builtin_inff();
#pragma unroll
    for (int nj = 0; nj < 4; nj++) {
#pragma unroll
      for (int r = 0; r < 4; r++) {
        int kg = kv0 + nj * 16 + quad * 4 + r;
        float v = accs[nj][r] * scale;
        v = (kg > qg || kg >= SEQ) ? -__builtin_inff() : v;
        sv[nj][r] = v;
        tmx = fmaxf(tmx, v);
      }
    }
    tmx = fmaxf(tmx, __shfl_xor(tmx, 16));
    tmx = fmaxf(tmx, __shfl_xor(tmx, 32));
    float mn = fmaxf(m_run, tmx);
    float a  = __expf(m_run - mn);
    float rs = 0.f;
#pragma unroll
    for (int nj = 0; nj < 4; nj++) {
      s4v pp;
#pragma unroll
      for (int r = 0; r < 4; r++) {
        float p = __expf(sv[nj][r] - mn);
        rs += p;
        pp[r] = bf16_of(p);
      }
      *(s4v*)(Pt + (w * 16 + c) * 72 + nj * 16 + quad * 4) = pp;
    }
    rs += __shfl_xor(rs, 16);
    rs += __shfl_xor(rs, 32);
    m_run = mn;
    l_run = l_run * a + rs;
#pragma unroll
    for (int dj = 0; dj < 8; dj++) acco[dj] *= a;

    // O^T += V^T * P^T   (Pt rows are wave-private; same-wave LDS in-order)
#pragma unroll
    for (int kk = 0; kk < 2; kk++) {
      s8v pf = *(const s8v*)(Pt + (w * 16 + c) * 72 + kk * 32 + quad * 8);
      const int kc = kk * 4 + quad;
#pragma unroll
      for (int dj = 0; dj < 8; dj++) {
        int m = dj * 16 + c;
        s8v vf = *(const s8v*)(Vsb + m * 64 + ((kc ^ (m & 7)) << 3));
        acco[dj] = mfma16(vf, pf, acco[dj]);
      }
    }
  };

  const int tmax = qt;             // (q0+63)>>6 == qt; qt <= 32 == (SEQ-1)>>6
  do_prefetch(0, Ks0, Vs0);
  int t = 0;
  for (;;) {
    __syncthreads();               // drain: tile-t loads (buf0) complete for all
    do_prefetch(t + 1, Ks1, Vs1);  // overshoot at t==tmax is in-bounds (rows < NPAD)
    do_tile(t, Ks0, Vs0);
    if (t == tmax) break;
    t++;
    __syncthreads();
    do_prefetch(t + 1, Ks0, Vs0);
    do_tile(t, Ks1, Vs1);
    if (t == tmax) break;
    t++;
  }
  __syncthreads();                 // drain trailing prefetch before LDS teardown

  const float inv = 1.f / l_run;
  const size_t orow = ((size_t)b * NPAD + q0 + w * 16 + c) * 1024 + h * 128;
#pragma unroll
  for (int dj = 0; dj < 8; dj++) {
    s4v ov;
#pragma unroll
    for (int r = 0; r < 4; r++) ov[r] = bf16_of(acco[dj][r] * inv);
    *(s4v*)(ao + orow + dj * 16 + quad * 4) = ov;
  }
}

// ---------------------------------------------------------------------------
__global__ void cls_copy(const float* __restrict__ xf, float* __restrict__ out_cls)
{
  int idx = blockIdx.x * 256 + threadIdx.x;   // 2048 total
  int b = idx >> 10, d = idx & 1023;
  out_cls[idx] = xf[(size_t)b * NPAD * 1024 + d];
}

__global__ void final_copy(const float* __restrict__ xf, float* __restrict__ out)
{
  size_t idx = (size_t)blockIdx.x * 256 + threadIdx.x;  // 1,049,088 total (exact)
  size_t e = idx * 4;
  size_t r = e >> 10;
  int d = (int)(e & 1023);
  int b = (int)(r / SEQ);
  int i = (int)(r % SEQ);
  *(float4*)(out + e) = *(const float4*)(xf + ((size_t)b * NPAD + i) * 1024 + d);
}

// ---------------------------------------------------------------------------
extern "C" void kernel_launch(void* const* d_in, const int* in_sizes, int n_in,
                              void* d_out, int out_size, void* d_ws, size_t ws_size,
                              hipStream_t stream)
{
  const float* x   = (const float*)d_in[0];
  const float* cls = (const float*)d_in[1];
  const float* Wqkv_s[2] = {(const float*)d_in[2], (const float*)d_in[9]};
  const float* Wo_s[2]   = {(const float*)d_in[3], (const float*)d_in[10]};
  const float* bo_s[2]   = {(const float*)d_in[4], (const float*)d_in[11]};
  const float* W1_s[2]   = {(const float*)d_in[5], (const float*)d_in[12]};
  const float* b1_s[2]   = {(const float*)d_in[6], (const float*)d_in[13]};
  const float* W2_s[2]   = {(const float*)d_in[7], (const float*)d_in[14]};
  const float* b2_s[2]   = {(const float*)d_in[8], (const float*)d_in[15]};
  float* out = (float*)d_out;

  char* ws = (char*)d_ws;
  size_t off = 0;
  auto alloc = [&](size_t bytes) -> void* {
    void* p = ws + off;
    off += (bytes + 255) & ~(size_t)255;
    return p;
  };
  float* xf   = (float*)alloc((size_t)MPAD * 1024 * 4);
  short* xb   = (short*)alloc((size_t)MPAD * 1024 * 2);
  short* qkvb = (short*)alloc((size_t)MPAD * 3072 * 2);
  short* vT   = (short*)alloc((size_t)MPAD * 1024 * 2);
  short* aob  = (short*)alloc((size_t)MPAD * 1024 * 2);
  short* hb   = (short*)alloc((size_t)MPAD * 4096 * 2);
  short* wtq  = (short*)alloc((size_t)3072 * 1024 * 2);
  short* wto  = (short*)alloc((size_t)1024 * 1024 * 2);
  short* wt1  = (short*)alloc((size_t)4096 * 1024 * 2);
  short* wt2  = (short*)alloc((size_t)1024 * 4096 * 2);

  concat_cast<<<4352, 256, 0, stream>>>(x, cls, xf, xb);

  for (int layer = 0; layer < 8; layer++) {
    int s = layer >> 2, li = layer & 3;
    const float* Wqkv = Wqkv_s[s] + (size_t)li * 1024 * 3072;
    const float* Wo   = Wo_s[s]   + (size_t)li * 1024 * 1024;
    const float* bo   = bo_s[s]   + (size_t)li * 1024;
    const float* W1   = W1_s[s]   + (size_t)li * 1024 * 4096;
    const float* b1   = b1_s[s]   + (size_t)li * 4096;
    const float* W2   = W2_s[s]   + (size_t)li * 4096 * 1024;
    const float* b2   = b2_s[s]   + (size_t)li * 1024;

    wcast_all<<<3072, 256, 0, stream>>>(Wqkv, Wo, W1, W2, wtq, wto, wt1, wt2);

    // qkv = x @ Wqkv            (M=4352, N=3072, K=1024)
    gemm_bt<0><<<dim3(24, 34), 256, 0, stream>>>(xb, wtq, nullptr, nullptr, qkvb, 3072, 1024);
    v_transpose<<<dim3(34, 16, 2), 256, 0, stream>>>(qkvb, vT);
    flash_attn<<<dim3(33, 8, 2), 256, 0, stream>>>(qkvb, vT, aob);
    // x += attn @ Wo + bo       (N=1024, K=1024)
    gemm_bt64<2><<<dim3(8, 68), 256, 0, stream>>>(aob, wto, bo, xf, xb, 1024, 1024);
    // h = gelu(x @ W1 + b1)     (N=4096, K=1024)
    gemm_bt<1><<<dim3(32, 34), 256, 0, stream>>>(xb, wt1, b1, nullptr, hb, 4096, 1024);
    // x += h @ W2 + b2          (N=1024, K=4096)
    gemm_bt64<2><<<dim3(8, 68), 256, 0, stream>>>(hb, wt2, b2, xf, xb, 1024, 4096);

    if (layer == 3)
      cls_copy<<<8, 256, 0, stream>>>(xf, out + (size_t)BATCH * SEQ * 1024);
  }

  final_copy<<<4098, 256, 0, stream>>>(xf, out);
  (void)in_sizes; (void)n_in; (void)out_size; (void)ws_size;
}